// Round 1
// baseline (802.374 us; speedup 1.0000x reference)
//
#include <hip/hip_runtime.h>

// ElectrostaticEnergyLayer: per-pair shielded/switched Coulomb energy,
// scatter-added to atoms by idx_i.
//
// E_ord = 1/D + D/100 - 0.2 ; E_sh = 1/sqrt(D^2+1) + sqrt(D^2+1)/100 - 0.2
// switch = phi(D/2): 1 - x^3(x(6x-15)+10) for x<1 else 0
// Eele = KEHALF*Qi*Qj*(sw*E_sh + (1-sw)*E_ord), zeroed for D > 10.

#define KEHALF 7.199822675975274f

__global__ __launch_bounds__(256) void ee_pair_kernel(
    const float* __restrict__ Dij,
    const float* __restrict__ Qa,
    const int*   __restrict__ idx_i,
    const int*   __restrict__ idx_j,
    float*       __restrict__ out,
    int P)
{
    int t = blockIdx.x * blockDim.x + threadIdx.x;
    long base = (long)t * 4;
    if (base >= P) return;

    float4 d4 = *reinterpret_cast<const float4*>(Dij + base);
    int4   i4 = *reinterpret_cast<const int4*>(idx_i + base);
    int4   j4 = *reinterpret_cast<const int4*>(idx_j + base);

    float D[4] = {d4.x, d4.y, d4.z, d4.w};
    int   ii[4] = {i4.x, i4.y, i4.z, i4.w};
    int   jj[4] = {j4.x, j4.y, j4.z, j4.w};

#pragma unroll
    for (int k = 0; k < 4; ++k) {
        float d  = D[k];
        float Qi = Qa[ii[k]];
        float Qj = Qa[jj[k]];

        float dsh = sqrtf(d * d + 1.0f);
        float x   = 0.5f * d;                 // D / (SR_CUTOFF/2) / 2 => D/2 with sr=2.0
        float x3  = x * x * x;
        float sw  = (x < 1.0f) ? 1.0f - x3 * (x * (6.0f * x - 15.0f) + 10.0f) : 0.0f;

        float Eo = 1.0f / d   + d   * 0.01f - 0.2f;
        float Es = 1.0f / dsh + dsh * 0.01f - 0.2f;

        float e = KEHALF * Qi * Qj * (sw * Es + (1.0f - sw) * Eo);

        if (d <= 10.0f) {
            atomicAdd(out + ii[k], e);
        }
    }
}

extern "C" void kernel_launch(void* const* d_in, const int* in_sizes, int n_in,
                              void* d_out, int out_size, void* d_ws, size_t ws_size,
                              hipStream_t stream) {
    const float* Dij   = (const float*)d_in[0];
    const float* Qa    = (const float*)d_in[1];
    const int*   idx_i = (const int*)d_in[2];
    const int*   idx_j = (const int*)d_in[3];
    float*       out   = (float*)d_out;

    int P = in_sizes[0];

    // Harness poisons d_out with 0xAA before every launch; we accumulate, so zero it.
    hipMemsetAsync(out, 0, (size_t)out_size * sizeof(float), stream);

    int threads = (P + 3) / 4;
    int block = 256;
    int grid = (threads + block - 1) / block;
    ee_pair_kernel<<<grid, block, 0, stream>>>(Dij, Qa, idx_i, idx_j, out, P);
}